// Round 1
// baseline (223.998 us; speedup 1.0000x reference)
//
#include <hip/hip_runtime.h>
#include <math.h>

#define BN 2
#define SN 1024
#define TN 1024
#define DS 128
#define DT 64
#define HN 64
#define LN_EPS 1e-5f

__device__ __forceinline__ float wave_sum(float v) {
#pragma unroll
  for (int m = 32; m >= 1; m >>= 1) v += __shfl_xor(v, m, 64);
  return v;
}

// ---------------- Kernel 1a: source adapter ----------------
// s_ad = relu(LN(src@sW1+sb1))@sW2+sb2 ; sc = s_ad@cW_s ; sstats = {B_s, Qs}
__global__ __launch_bounds__(256) void k_source(
    const float* __restrict__ src,
    const float* __restrict__ sW1, const float* __restrict__ sb1,
    const float* __restrict__ sg, const float* __restrict__ sbeta,
    const float* __restrict__ sW2, const float* __restrict__ sb2,
    const float* __restrict__ cW,
    float* __restrict__ s_ad, float* __restrict__ sc, float* __restrict__ sstats)
{
  __shared__ float xbuf[4][DS];
  __shared__ float rbuf[4][HN];
  int w = threadIdx.x >> 6, lane = threadIdx.x & 63;
  int row = blockIdx.x * 4 + w;  // 0..2047
  xbuf[w][lane]      = src[row * DS + lane];
  xbuf[w][lane + 64] = src[row * DS + 64 + lane];
  __syncthreads();
  float h1 = sb1[lane];
#pragma unroll 8
  for (int k = 0; k < DS; ++k) h1 = fmaf(xbuf[w][k], sW1[k * HN + lane], h1);
  float s1 = wave_sum(h1), s2 = wave_sum(h1 * h1);
  float m = s1 * (1.f / HN);
  float var = s2 * (1.f / HN) - m * m;
  float r = fmaxf(0.f, (h1 - m) * rsqrtf(var + LN_EPS) * sg[lane] + sbeta[lane]);
  rbuf[w][lane] = r;
  __syncthreads();
  float a2 = sb2[lane];
#pragma unroll 8
  for (int j = 0; j < HN; ++j) a2 = fmaf(rbuf[w][j], sW2[j * HN + lane], a2);
  s_ad[row * HN + lane] = a2;
  __syncthreads();
  rbuf[w][lane] = a2;
  __syncthreads();
  float scv = 0.f;
#pragma unroll 8
  for (int j = 0; j < HN; ++j) scv = fmaf(rbuf[w][j], cW[(HN + j) * HN + lane], scv);
  sc[row * HN + lane] = scv;
  float bs = wave_sum(scv), qs = wave_sum(scv * scv);
  if (lane == 0) { sstats[row * 2] = bs; sstats[row * 2 + 1] = qs; }
}

// ---------------- Kernel 1b: target adapter ----------------
// t_ad ; tc = t_ad@cW_t + cb ; tstats = {A_t, Qt, gate}
__global__ __launch_bounds__(256) void k_target(
    const float* __restrict__ tgt,
    const float* __restrict__ tW1, const float* __restrict__ tb1,
    const float* __restrict__ tg, const float* __restrict__ tbeta,
    const float* __restrict__ tW2, const float* __restrict__ tb2,
    const float* __restrict__ cW, const float* __restrict__ cb,
    float* __restrict__ t_ad, float* __restrict__ tc, float* __restrict__ tstats)
{
  __shared__ float xbuf[4][DT];
  __shared__ float rbuf[4][HN];
  int w = threadIdx.x >> 6, lane = threadIdx.x & 63;
  int row = blockIdx.x * 4 + w;  // 0..2047
  xbuf[w][lane] = tgt[row * DT + lane];
  __syncthreads();
  float h1 = tb1[lane];
#pragma unroll 8
  for (int k = 0; k < DT; ++k) h1 = fmaf(xbuf[w][k], tW1[k * HN + lane], h1);
  float s1 = wave_sum(h1), s2 = wave_sum(h1 * h1);
  float m = s1 * (1.f / HN);
  float var = s2 * (1.f / HN) - m * m;
  float r = fmaxf(0.f, (h1 - m) * rsqrtf(var + LN_EPS) * tg[lane] + tbeta[lane]);
  rbuf[w][lane] = r;
  __syncthreads();
  float a2 = tb2[lane];
#pragma unroll 8
  for (int j = 0; j < HN; ++j) a2 = fmaf(rbuf[w][j], tW2[j * HN + lane], a2);
  t_ad[row * HN + lane] = a2;
  float asum = wave_sum(a2);
  float gate = 1.f / (1.f + __expf(-asum * (1.f / HN)));
  __syncthreads();
  rbuf[w][lane] = a2;
  __syncthreads();
  float tcv = cb[lane];
#pragma unroll 8
  for (int j = 0; j < HN; ++j) tcv = fmaf(rbuf[w][j], cW[j * HN + lane], tcv);
  tc[row * HN + lane] = tcv;
  float A = wave_sum(tcv), Q = wave_sum(tcv * tcv);
  if (lane == 0) { tstats[row * 3] = A; tstats[row * 3 + 1] = Q; tstats[row * 3 + 2] = gate; }
}

// ---------------- Kernel 2: pairwise scores + softmax + transfer ----------------
#define TT 2
__global__ __launch_bounds__(128) void k_pair(
    const float* __restrict__ cg, const float* __restrict__ cbeta,
    const float* __restrict__ simW, const float* __restrict__ simb,
    const float* __restrict__ s_ad, const float* __restrict__ sc,
    const float* __restrict__ sstats,
    const float* __restrict__ t_ad, const float* __restrict__ tc,
    const float* __restrict__ tstats,
    float* __restrict__ out_adapted, float* __restrict__ out_scores)
{
  __shared__ float sc_tile[64 * 64];   // xor-swizzled, 16B-aligned rows
  __shared__ float sl[TT][SN];
  int w = threadIdx.x >> 6, lane = threadIdx.x & 63;
  int b = blockIdx.x / (TN / TT);
  int t = (blockIdx.x % (TN / TT)) * TT + w;
  int rt = __builtin_amdgcn_readfirstlane(b * TN + t);

  float A    = tstats[rt * 3 + 0];
  float Qt   = tstats[rt * 3 + 1];
  float gate = tstats[rt * 3 + 2];
  float simb0 = simb[0];
  float lsum = 0.f;

  const float4* scg = (const float4*)(sc + b * SN * HN);

  for (int c = 0; c < SN / 64; ++c) {
    __syncthreads();
    // stage sc chunk (64 s-rows x 64 h) into LDS with xor swizzle
#pragma unroll
    for (int it = 0; it < 8; ++it) {
      int j = it * 128 + threadIdx.x;      // 0..1023 float4s
      int srow = j >> 4, g = j & 15;
      float4 v = scg[(c * 64 + srow) * 16 + g];
      int gp = g ^ (srow & 15);
      *(float4*)&sc_tile[srow * 64 + gp * 4] = v;
    }
    __syncthreads();

    int s = c * 64 + lane;
    float2 bq = *(const float2*)&sstats[(b * SN + s) * 2];

    // pass 1: cross-term D = sum_h tc_h * sc_h
    float D = 0.f;
#pragma unroll
    for (int g = 0; g < 16; ++g) {
      int gp = g ^ (lane & 15);
      float4 v = *(const float4*)&sc_tile[lane * 64 + gp * 4];
      int h = g * 4;
      D = fmaf(tc[rt * HN + h + 0], v.x, D);
      D = fmaf(tc[rt * HN + h + 1], v.y, D);
      D = fmaf(tc[rt * HN + h + 2], v.z, D);
      D = fmaf(tc[rt * HN + h + 3], v.w, D);
    }
    float mean  = (A + bq.x) * (1.f / HN);
    float e2    = (Qt + bq.y + 2.f * D) * (1.f / HN);
    float var   = e2 - mean * mean;
    float alpha = rsqrtf(var + LN_EPS);

    // pass 2: dot = sum_h relu((pre-m)*alpha*cg + cbeta) * simW
    float dot = 0.f;
#pragma unroll
    for (int g = 0; g < 16; ++g) {
      int gp = g ^ (lane & 15);
      float4 v = *(const float4*)&sc_tile[lane * 64 + gp * 4];
      int h = g * 4;
      {
        float t0 = alpha * cg[h + 0];
        float t1 = fmaf(-mean, t0, cbeta[h + 0]);
        float n  = fmaf(tc[rt * HN + h + 0] + v.x, t0, t1);
        dot = fmaf(fmaxf(n, 0.f), simW[h + 0], dot);
      }
      {
        float t0 = alpha * cg[h + 1];
        float t1 = fmaf(-mean, t0, cbeta[h + 1]);
        float n  = fmaf(tc[rt * HN + h + 1] + v.y, t0, t1);
        dot = fmaf(fmaxf(n, 0.f), simW[h + 1], dot);
      }
      {
        float t0 = alpha * cg[h + 2];
        float t1 = fmaf(-mean, t0, cbeta[h + 2]);
        float n  = fmaf(tc[rt * HN + h + 2] + v.z, t0, t1);
        dot = fmaf(fmaxf(n, 0.f), simW[h + 2], dot);
      }
      {
        float t0 = alpha * cg[h + 3];
        float t1 = fmaf(-mean, t0, cbeta[h + 3]);
        float n  = fmaf(tc[rt * HN + h + 3] + v.w, t0, t1);
        dot = fmaf(fmaxf(n, 0.f), simW[h + 3], dot);
      }
    }
    float score = 1.f / (1.f + __expf(-(dot + simb0)));
    out_scores[rt * SN + s] = score;
    sl[w][s] = score;
    lsum += __expf(score);   // scores in (0,1): no max-subtract needed
  }

  float total = wave_sum(lsum);
  float inv = 1.f / total;

  // convert stored scores to unnormalized softmax weights
  __syncthreads();
#pragma unroll
  for (int i = 0; i < 16; ++i) {
    int s = i * 64 + lane;
    sl[w][s] = __expf(sl[w][s]);
  }
  __syncthreads();

  // transferred[h] = inv * sum_s p_s * s_ad[s,h]   (lane = h)
  float acc = 0.f;
  const float* sadb = s_ad + b * SN * HN;
#pragma unroll 2
  for (int s4 = 0; s4 < SN / 4; ++s4) {
    float4 p4 = *(const float4*)&sl[w][s4 * 4];
    acc = fmaf(p4.x, sadb[(s4 * 4 + 0) * HN + lane], acc);
    acc = fmaf(p4.y, sadb[(s4 * 4 + 1) * HN + lane], acc);
    acc = fmaf(p4.z, sadb[(s4 * 4 + 2) * HN + lane], acc);
    acc = fmaf(p4.w, sadb[(s4 * 4 + 3) * HN + lane], acc);
  }
  acc *= inv;

  float tad = t_ad[rt * HN + lane];
  out_adapted[rt * HN + lane] = tad * (1.f - gate) + acc * gate;
}

extern "C" void kernel_launch(void* const* d_in, const int* in_sizes, int n_in,
                              void* d_out, int out_size, void* d_ws, size_t ws_size,
                              hipStream_t stream) {
  const float* src   = (const float*)d_in[0];
  const float* tgt   = (const float*)d_in[1];
  const float* sW1   = (const float*)d_in[2];
  const float* sb1   = (const float*)d_in[3];
  const float* sg    = (const float*)d_in[4];
  const float* sbeta = (const float*)d_in[5];
  const float* sW2   = (const float*)d_in[6];
  const float* sb2   = (const float*)d_in[7];
  const float* tW1   = (const float*)d_in[8];
  const float* tb1   = (const float*)d_in[9];
  const float* tg    = (const float*)d_in[10];
  const float* tbeta = (const float*)d_in[11];
  const float* tW2   = (const float*)d_in[12];
  const float* tb2   = (const float*)d_in[13];
  const float* cW    = (const float*)d_in[14];
  const float* cb    = (const float*)d_in[15];
  const float* cg    = (const float*)d_in[16];
  const float* cbeta = (const float*)d_in[17];
  const float* simW  = (const float*)d_in[18];
  const float* simb  = (const float*)d_in[19];

  float* ws     = (float*)d_ws;
  float* s_ad   = ws;             // 131072
  float* sc     = ws + 131072;    // 131072
  float* sstats = ws + 262144;    // 4096
  float* t_ad   = ws + 266240;    // 131072
  float* tc     = ws + 397312;    // 131072
  float* tstats = ws + 528384;    // 6144

  float* out_adapted = (float*)d_out;            // B*T*H = 131072
  float* out_scores  = (float*)d_out + 131072;   // B*T*S = 2097152

  hipLaunchKernelGGL(k_source, dim3(512), dim3(256), 0, stream,
                     src, sW1, sb1, sg, sbeta, sW2, sb2, cW, s_ad, sc, sstats);
  hipLaunchKernelGGL(k_target, dim3(512), dim3(256), 0, stream,
                     tgt, tW1, tb1, tg, tbeta, tW2, tb2, cW, cb, t_ad, tc, tstats);
  hipLaunchKernelGGL(k_pair, dim3(BN * (TN / TT)), dim3(128), 0, stream,
                     cg, cbeta, simW, simb, s_ad, sc, sstats, t_ad, tc, tstats,
                     out_adapted, out_scores);
}

// Round 2
// 207.649 us; speedup vs baseline: 1.0787x; 1.0787x over previous
//
#include <hip/hip_runtime.h>
#include <math.h>

#define BN 2
#define SN 1024
#define TN 1024
#define DS 128
#define DT 64
#define HN 64
#define LN_EPS 1e-5f

__device__ __forceinline__ float wave_sum(float v) {
#pragma unroll
  for (int m = 32; m >= 1; m >>= 1) v += __shfl_xor(v, m, 64);
  return v;
}

// ---------------- Kernel 1: both adapters in one launch ----------------
__global__ __launch_bounds__(256) void k_adapters(
    const float* __restrict__ src, const float* __restrict__ tgt,
    const float* __restrict__ sW1, const float* __restrict__ sb1,
    const float* __restrict__ sg, const float* __restrict__ sbeta,
    const float* __restrict__ sW2, const float* __restrict__ sb2,
    const float* __restrict__ tW1, const float* __restrict__ tb1,
    const float* __restrict__ tg, const float* __restrict__ tbeta,
    const float* __restrict__ tW2, const float* __restrict__ tb2,
    const float* __restrict__ cW, const float* __restrict__ cb,
    float* __restrict__ s_ad, float* __restrict__ sc, float* __restrict__ sstats,
    float* __restrict__ t_ad, float* __restrict__ tc, float* __restrict__ tstats)
{
  __shared__ float xbuf[4][DS];
  __shared__ float rbuf[4][HN];
  int w = threadIdx.x >> 6, lane = threadIdx.x & 63;

  if (blockIdx.x < 512) {
    int row = blockIdx.x * 4 + w;  // 0..2047
    xbuf[w][lane]      = src[row * DS + lane];
    xbuf[w][lane + 64] = src[row * DS + 64 + lane];
    float a0 = 0.f, a1 = 0.f, a2_ = 0.f, a3 = 0.f;
#pragma unroll 8
    for (int k = 0; k < DS; k += 4) {
      a0  = fmaf(xbuf[w][k + 0], sW1[(k + 0) * HN + lane], a0);
      a1  = fmaf(xbuf[w][k + 1], sW1[(k + 1) * HN + lane], a1);
      a2_ = fmaf(xbuf[w][k + 2], sW1[(k + 2) * HN + lane], a2_);
      a3  = fmaf(xbuf[w][k + 3], sW1[(k + 3) * HN + lane], a3);
    }
    float h1 = ((a0 + a1) + (a2_ + a3)) + sb1[lane];
    float s1 = wave_sum(h1), s2 = wave_sum(h1 * h1);
    float m = s1 * (1.f / HN);
    float var = s2 * (1.f / HN) - m * m;
    float r = fmaxf(0.f, (h1 - m) * rsqrtf(var + LN_EPS) * sg[lane] + sbeta[lane]);
    rbuf[w][lane] = r;
    float b0 = 0.f, b1 = 0.f, b2 = 0.f, b3 = 0.f;
#pragma unroll 4
    for (int j = 0; j < HN; j += 4) {
      b0 = fmaf(rbuf[w][j + 0], sW2[(j + 0) * HN + lane], b0);
      b1 = fmaf(rbuf[w][j + 1], sW2[(j + 1) * HN + lane], b1);
      b2 = fmaf(rbuf[w][j + 2], sW2[(j + 2) * HN + lane], b2);
      b3 = fmaf(rbuf[w][j + 3], sW2[(j + 3) * HN + lane], b3);
    }
    float a2 = ((b0 + b1) + (b2 + b3)) + sb2[lane];
    s_ad[row * HN + lane] = a2;
    rbuf[w][lane] = a2;
    float c0 = 0.f, c1 = 0.f, c2 = 0.f, c3 = 0.f;
#pragma unroll 4
    for (int j = 0; j < HN; j += 4) {
      c0 = fmaf(rbuf[w][j + 0], cW[(HN + j + 0) * HN + lane], c0);
      c1 = fmaf(rbuf[w][j + 1], cW[(HN + j + 1) * HN + lane], c1);
      c2 = fmaf(rbuf[w][j + 2], cW[(HN + j + 2) * HN + lane], c2);
      c3 = fmaf(rbuf[w][j + 3], cW[(HN + j + 3) * HN + lane], c3);
    }
    float scv = (c0 + c1) + (c2 + c3);
    sc[row * HN + lane] = scv;
    float bs = wave_sum(scv), qs = wave_sum(scv * scv);
    if (lane == 0) { sstats[row * 2] = bs; sstats[row * 2 + 1] = qs; }
  } else {
    int row = (blockIdx.x - 512) * 4 + w;  // 0..2047
    xbuf[w][lane] = tgt[row * DT + lane];
    float a0 = 0.f, a1 = 0.f, a2_ = 0.f, a3 = 0.f;
#pragma unroll 4
    for (int k = 0; k < DT; k += 4) {
      a0  = fmaf(xbuf[w][k + 0], tW1[(k + 0) * HN + lane], a0);
      a1  = fmaf(xbuf[w][k + 1], tW1[(k + 1) * HN + lane], a1);
      a2_ = fmaf(xbuf[w][k + 2], tW1[(k + 2) * HN + lane], a2_);
      a3  = fmaf(xbuf[w][k + 3], tW1[(k + 3) * HN + lane], a3);
    }
    float h1 = ((a0 + a1) + (a2_ + a3)) + tb1[lane];
    float s1 = wave_sum(h1), s2 = wave_sum(h1 * h1);
    float m = s1 * (1.f / HN);
    float var = s2 * (1.f / HN) - m * m;
    float r = fmaxf(0.f, (h1 - m) * rsqrtf(var + LN_EPS) * tg[lane] + tbeta[lane]);
    rbuf[w][lane] = r;
    float b0 = 0.f, b1 = 0.f, b2 = 0.f, b3 = 0.f;
#pragma unroll 4
    for (int j = 0; j < HN; j += 4) {
      b0 = fmaf(rbuf[w][j + 0], tW2[(j + 0) * HN + lane], b0);
      b1 = fmaf(rbuf[w][j + 1], tW2[(j + 1) * HN + lane], b1);
      b2 = fmaf(rbuf[w][j + 2], tW2[(j + 2) * HN + lane], b2);
      b3 = fmaf(rbuf[w][j + 3], tW2[(j + 3) * HN + lane], b3);
    }
    float a2 = ((b0 + b1) + (b2 + b3)) + tb2[lane];
    t_ad[row * HN + lane] = a2;
    float asum = wave_sum(a2);
    float gate = 1.f / (1.f + __expf(-asum * (1.f / HN)));
    rbuf[w][lane] = a2;
    float c0 = 0.f, c1 = 0.f, c2 = 0.f, c3 = 0.f;
#pragma unroll 4
    for (int j = 0; j < HN; j += 4) {
      c0 = fmaf(rbuf[w][j + 0], cW[(j + 0) * HN + lane], c0);
      c1 = fmaf(rbuf[w][j + 1], cW[(j + 1) * HN + lane], c1);
      c2 = fmaf(rbuf[w][j + 2], cW[(j + 2) * HN + lane], c2);
      c3 = fmaf(rbuf[w][j + 3], cW[(j + 3) * HN + lane], c3);
    }
    float tcv = ((c0 + c1) + (c2 + c3)) + cb[lane];
    tc[row * HN + lane] = tcv;
    float A = wave_sum(tcv), Q = wave_sum(tcv * tcv);
    if (lane == 0) { tstats[row * 3] = A; tstats[row * 3 + 1] = Q; tstats[row * 3 + 2] = gate; }
  }
}

// ---------------- Kernel 2: scores (split-s, high occupancy) ----------------
__global__ __launch_bounds__(256, 6) void k_scores(
    const float* __restrict__ cg, const float* __restrict__ cbeta,
    const float* __restrict__ simW, const float* __restrict__ simb,
    const float* __restrict__ sc, const float* __restrict__ sstats,
    const float* __restrict__ tc, const float* __restrict__ tstats,
    float* __restrict__ out_scores)
{
  __shared__ float tile[64 * 64];
  int tid = threadIdx.x;
  int w = tid >> 6, lane = tid & 63;
  int sblk = blockIdx.x & 3;
  int tblk = (blockIdx.x >> 2) & (TN / 4 - 1);
  int b    = blockIdx.x >> 10;
  int t = tblk * 4 + w;
  int rt = __builtin_amdgcn_readfirstlane(b * TN + t);

  float A  = tstats[rt * 3 + 0];
  float Qt = tstats[rt * 3 + 1];
  const float* tcr = tc + rt * HN;
  float simb0 = simb[0];

  const float4* scg = (const float4*)(sc + b * SN * HN);

#pragma unroll 1
  for (int c = 0; c < 4; ++c) {
    int s0 = sblk * 256 + c * 64;
    __syncthreads();
#pragma unroll
    for (int it = 0; it < 4; ++it) {
      int j = it * 256 + tid;
      int srow = j >> 4, g = j & 15;
      float4 v = scg[(s0 + srow) * 16 + g];
      int gp = g ^ (srow & 15);
      *(float4*)&tile[srow * 64 + gp * 4] = v;
    }
    __syncthreads();

    int s = s0 + lane;
    float2 bq = *(const float2*)&sstats[(b * SN + s) * 2];

    float D = 0.f;
#pragma unroll
    for (int g = 0; g < 16; ++g) {
      int gp = g ^ (lane & 15);
      float4 v = *(const float4*)&tile[lane * 64 + gp * 4];
      const float* vv = (const float*)&v;
#pragma unroll
      for (int j = 0; j < 4; ++j) D = fmaf(tcr[g * 4 + j], vv[j], D);
    }
    float mean  = (A + bq.x) * (1.f / HN);
    float e2    = (Qt + bq.y + 2.f * D) * (1.f / HN);
    float var   = e2 - mean * mean;
    float alpha = rsqrtf(var + LN_EPS);

    float dot0 = 0.f, dot1 = 0.f;
#pragma unroll
    for (int g = 0; g < 16; ++g) {
      int gp = g ^ (lane & 15);
      float4 v = *(const float4*)&tile[lane * 64 + gp * 4];
      const float* vv = (const float*)&v;
#pragma unroll
      for (int j = 0; j < 4; ++j) {
        int h = g * 4 + j;
        float P = alpha * cg[h];
        float q = fmaf(-mean, P, cbeta[h]);
        float u = vv[j] + tcr[h];
        float n = fmaf(u, P, q);
        if (j & 1) dot1 = fmaf(fmaxf(n, 0.f), simW[h], dot1);
        else       dot0 = fmaf(fmaxf(n, 0.f), simW[h], dot0);
      }
    }
    float dot = dot0 + dot1;
    float score = 1.f / (1.f + __expf(-(dot + simb0)));
    out_scores[rt * SN + s] = score;
  }
}

// ---------------- Kernel 3: softmax + transfer + gate ----------------
__global__ __launch_bounds__(256) void k_combine(
    const float* __restrict__ s_ad, const float* __restrict__ t_ad,
    const float* __restrict__ tstats, const float* __restrict__ scores,
    float* __restrict__ out_adapted)
{
  __shared__ float eb[4][SN];
  int w = threadIdx.x >> 6, lane = threadIdx.x & 63;
  int tblk = blockIdx.x & (TN / 4 - 1);
  int b    = blockIdx.x >> 8;
  int t = tblk * 4 + w;
  int rt = __builtin_amdgcn_readfirstlane(b * TN + t);

  float lsum = 0.f;
#pragma unroll 4
  for (int c = 0; c < 16; ++c) {
    float e = __expf(scores[rt * SN + c * 64 + lane]);
    eb[w][c * 64 + lane] = e;
    lsum += e;
  }
  float inv = 1.f / wave_sum(lsum);

  const float* sadb = s_ad + b * SN * HN;
  float ac0 = 0.f, ac1 = 0.f, ac2 = 0.f, ac3 = 0.f;
#pragma unroll 2
  for (int s = 0; s < SN; s += 4) {
    ac0 = fmaf(eb[w][s + 0], sadb[(s + 0) * HN + lane], ac0);
    ac1 = fmaf(eb[w][s + 1], sadb[(s + 1) * HN + lane], ac1);
    ac2 = fmaf(eb[w][s + 2], sadb[(s + 2) * HN + lane], ac2);
    ac3 = fmaf(eb[w][s + 3], sadb[(s + 3) * HN + lane], ac3);
  }
  float acc = ((ac0 + ac1) + (ac2 + ac3)) * inv;

  float gate = tstats[rt * 3 + 2];
  float tad = t_ad[rt * HN + lane];
  out_adapted[rt * HN + lane] = tad * (1.f - gate) + acc * gate;
}

extern "C" void kernel_launch(void* const* d_in, const int* in_sizes, int n_in,
                              void* d_out, int out_size, void* d_ws, size_t ws_size,
                              hipStream_t stream) {
  const float* src   = (const float*)d_in[0];
  const float* tgt   = (const float*)d_in[1];
  const float* sW1   = (const float*)d_in[2];
  const float* sb1   = (const float*)d_in[3];
  const float* sg    = (const float*)d_in[4];
  const float* sbeta = (const float*)d_in[5];
  const float* sW2   = (const float*)d_in[6];
  const float* sb2   = (const float*)d_in[7];
  const float* tW1   = (const float*)d_in[8];
  const float* tb1   = (const float*)d_in[9];
  const float* tg    = (const float*)d_in[10];
  const float* tbeta = (const float*)d_in[11];
  const float* tW2   = (const float*)d_in[12];
  const float* tb2   = (const float*)d_in[13];
  const float* cW    = (const float*)d_in[14];
  const float* cb    = (const float*)d_in[15];
  const float* cg    = (const float*)d_in[16];
  const float* cbeta = (const float*)d_in[17];
  const float* simW  = (const float*)d_in[18];
  const float* simb  = (const float*)d_in[19];

  float* ws     = (float*)d_ws;
  float* s_ad   = ws;             // 131072
  float* sc     = ws + 131072;    // 131072
  float* sstats = ws + 262144;    // 4096
  float* t_ad   = ws + 266240;    // 131072
  float* tc     = ws + 397312;    // 131072
  float* tstats = ws + 528384;    // 6144

  float* out_adapted = (float*)d_out;            // B*T*H
  float* out_scores  = (float*)d_out + 131072;   // B*T*S

  hipLaunchKernelGGL(k_adapters, dim3(1024), dim3(256), 0, stream,
                     src, tgt, sW1, sb1, sg, sbeta, sW2, sb2,
                     tW1, tb1, tg, tbeta, tW2, tb2, cW, cb,
                     s_ad, sc, sstats, t_ad, tc, tstats);
  hipLaunchKernelGGL(k_scores, dim3(BN * (TN / 4) * (SN / 256)), dim3(256), 0, stream,
                     cg, cbeta, simW, simb, sc, sstats, tc, tstats, out_scores);
  hipLaunchKernelGGL(k_combine, dim3(BN * (TN / 4)), dim3(256), 0, stream,
                     s_ad, t_ad, tstats, out_scores, out_adapted);
}